// Round 1
// baseline (2354.887 us; speedup 1.0000x reference)
//
#include <hip/hip_runtime.h>
#include <hip/hip_bf16.h>

// ============================================================================
// Net_89361089561102: 2-layer NF4-quantized transformer + cls head, MI355X.
// Round 1: correctness-first full forward.
//   - Generic 128x128 MFMA GEMM (bf16, 16x16x32), A via global_load_lds,
//     B either bf16 (global_load_lds) or fused NF4 dequant (LDS LUT).
//   - Attention materialized: scores fp32 -> softmax -> bf16 P -> ctx GEMM
//     with pre-transposed V (padded to 128 rows per head).
//   - Residual x fp32; head only for last token.
// ws layout (bytes):
//   x    @ 0          12,582,912  fp32 [1024,3072] residual
//   h    @ 12582912    6,291,456  bf16 [1024,3072] normed activations
//   big  @ 18874368   67,108,864  fp32 union: qkv[1024,9216] / scores[64,512,512] / gu[1024,16384]
//   P    @ 85983232   33,554,432  bf16 [64,512,512] attn probs
//   q    @ 119537664   6,291,456  bf16 [B,NH,S,96] (roped, pre-scaled 1/sqrt(96))
//   k    @ 125829120   6,291,456  bf16 [B,NH,S,96] (roped)
//   vT   @ 132120576   8,388,608  bf16 [64,128,512] (d-major, rows 96..127 garbage pad)
//   ctx  @ 140509184   6,291,456  bf16 [1024,3072]
//   ff   @ 146800640  16,777,216  bf16 [1024,8192]
//   cos  @ 163577856      98,304  fp32 [512,48]
//   sin  @ 163676160      98,304  fp32 [512,48]
//   xn   @ 163774464      24,576  fp32 [2,3072] final-rmsnorm rows
//   hcls @ 163799040       6,144  fp32 [2,768]
// total ~164 MB
// ============================================================================

typedef short bf16x8 __attribute__((ext_vector_type(8)));
typedef float f32x4  __attribute__((ext_vector_type(4)));

__device__ __constant__ float NF4C[16] = {
  -1.0f, -0.6961928009986877f, -0.5250730514526367f, -0.39491748809814453f,
  -0.28444138169288635f, -0.18477343022823334f, -0.09105003625154495f, 0.0f,
  0.07958029955625534f, 0.16093020141124725f, 0.24611230194568634f, 0.33791524171829224f,
  0.44070982933044434f, 0.5626170039176941f, 0.7229568362236023f, 1.0f };

__device__ __forceinline__ unsigned short f2bf(float f) {
  union { float f; unsigned int u; } v; v.f = f;
  unsigned int r = (v.u + 0x7fffu + ((v.u >> 16) & 1u)) >> 16;
  return (unsigned short)r;
}

__device__ __forceinline__ void gload16(const void* g, void* l) {
  __builtin_amdgcn_global_load_lds(
      (const __attribute__((address_space(1))) void*)g,
      (__attribute__((address_space(3))) void*)l, 16, 0, 0);
}

__device__ __forceinline__ float blk_sum(float v) {
  #pragma unroll
  for (int off = 32; off; off >>= 1) v += __shfl_xor(v, off, 64);
  __shared__ float r[4];
  __syncthreads();
  if ((threadIdx.x & 63) == 0) r[threadIdx.x >> 6] = v;
  __syncthreads();
  return r[0] + r[1] + r[2] + r[3];
}

// ---------------------------------------------------------------------------
// Generic GEMM: C[M,N] (optionally +=) = A[M,K](bf16,k-contig) * B[N,K]^T
// BNF4=1: B from NF4 packed words + absmax (W flat index = n*K + k).
// BNF4=0: B bf16 k-contig (ldb), staged via global_load_lds.
// OUTMODE: 0 = f32 store, 1 = f32 add, 2 = bf16 store.
// Batched via blockIdx.z decomposed as (z>>5, z&31) with element strides.
// Requires: K%32==0; A rows clamped to M-1 (safe for any M); B rows must
// exist up to ceil(N/128)*128 for BNF4=0 (true for all our uses).
// ---------------------------------------------------------------------------
template<int BNF4, int OUTMODE>
__global__ __launch_bounds__(256) void gemm_k(
    const unsigned short* __restrict__ A, int lda, size_t sAb, size_t sAh,
    const unsigned short* __restrict__ Bb, int ldb, size_t sBb, size_t sBh,
    const int* __restrict__ Wp, const float* __restrict__ Wa,
    void* __restrict__ Cv, int ldc, size_t sCb, size_t sCh,
    int M, int N, int K)
{
  __shared__ unsigned short lsA[128*32];
  __shared__ unsigned short lsB[128*32];
  __shared__ float lut[16];

  const int t = threadIdx.x, w = t >> 6, l = t & 63;
  const int bm = blockIdx.y, bn = blockIdx.x;
  const int z = blockIdx.z, zb = z >> 5, zh = z & 31;
  A += (size_t)zb*sAb + (size_t)zh*sAh;
  if (!BNF4) Bb += (size_t)zb*sBb + (size_t)zh*sBh;
  const size_t coff = (size_t)zb*sCb + (size_t)zh*sCh;

  if (BNF4) { if (t < 16) lut[t] = NF4C[t]; }
  __syncthreads();

  f32x4 acc[4][4] = {};
  const int wm = (w >> 1) * 64, wn = (w & 1) * 64;
  const int quad = l >> 4, lane16 = l & 15;
  const int arow = t >> 2, acol = (t & 3) << 3;

  for (int k0 = 0; k0 < K; k0 += 32) {
    // ---- stage A (async direct-to-LDS, linear [128][32]) ----
    {
      int r0 = bm*128 + arow;      if (r0 >= M) r0 = M - 1;
      int r1 = bm*128 + 64 + arow; if (r1 >= M) r1 = M - 1;
      gload16(A + (size_t)r0*lda + k0 + acol, (char*)lsA + w*1024);
      gload16(A + (size_t)r1*lda + k0 + acol, (char*)lsA + 4096 + w*1024);
    }
    // ---- stage B ----
    if (BNF4) {
      int r = t >> 1, part = t & 1;
      int n = bn*128 + r; if (n >= N) n = N - 1;
      size_t flat = (size_t)n * (size_t)K + (size_t)k0;   // %32 == 0
      int2 pk = ((const int2*)Wp)[flat/16 + part];
      float am = Wa[flat >> 6];
      unsigned int e[8];
      #pragma unroll
      for (int s = 0; s < 2; ++s) {
        int wd = s ? pk.y : pk.x;
        #pragma unroll
        for (int j = 0; j < 4; ++j) {
          float f0 = lut[(wd >> (8*j))     & 15] * am;
          float f1 = lut[(wd >> (8*j + 4)) & 15] * am;
          e[s*4+j] = (unsigned int)f2bf(f0) | ((unsigned int)f2bf(f1) << 16);
        }
      }
      uint4* dst = (uint4*)((char*)lsB + r*64 + part*32);
      dst[0] = make_uint4(e[0], e[1], e[2], e[3]);
      dst[1] = make_uint4(e[4], e[5], e[6], e[7]);
    } else {
      int r0 = bn*128 + arow;
      int r1 = r0 + 64;
      gload16(Bb + (size_t)r0*ldb + k0 + acol, (char*)lsB + w*1024);
      gload16(Bb + (size_t)r1*ldb + k0 + acol, (char*)lsB + 4096 + w*1024);
    }
    __syncthreads();

    // ---- fragments + MFMA ----
    bf16x8 af[4], bfr[4];
    #pragma unroll
    for (int i = 0; i < 4; ++i)
      af[i] = *(const bf16x8*)((const char*)lsA + (wm + i*16 + lane16)*64 + quad*16);
    #pragma unroll
    for (int j = 0; j < 4; ++j)
      bfr[j] = *(const bf16x8*)((const char*)lsB + (wn + j*16 + lane16)*64 + quad*16);
    #pragma unroll
    for (int i = 0; i < 4; ++i)
      #pragma unroll
      for (int j = 0; j < 4; ++j)
        acc[i][j] = __builtin_amdgcn_mfma_f32_16x16x32_bf16(af[i], bfr[j], acc[i][j], 0, 0, 0);
    __syncthreads();
  }

  // ---- store (C/D layout: col=lane&15, row=(lane>>4)*4+reg) ----
  float*          Cf = (float*)Cv + coff;
  unsigned short* Ch = (unsigned short*)Cv + coff;
  #pragma unroll
  for (int i = 0; i < 4; ++i) {
    #pragma unroll
    for (int j = 0; j < 4; ++j) {
      int m0 = bm*128 + wm + i*16 + quad*4;
      int n0 = bn*128 + wn + j*16 + lane16;
      if (n0 < N) {
        #pragma unroll
        for (int r = 0; r < 4; ++r) {
          int m = m0 + r;
          if (m < M) {
            float v = acc[i][j][r];
            if (OUTMODE == 0)      Cf[(size_t)m*ldc + n0] = v;
            else if (OUTMODE == 1) Cf[(size_t)m*ldc + n0] += v;
            else                   Ch[(size_t)m*ldc + n0] = f2bf(v);
          }
        }
      }
    }
  }
}

// ---------------------------------------------------------------------------
__global__ __launch_bounds__(256) void rope_table_k(float* __restrict__ ct, float* __restrict__ st) {
  int idx = blockIdx.x*256 + threadIdx.x;          // 512*48 entries
  int s = idx / 48, i = idx - 48*(idx/48);
  double inv = exp(-9.210340371976184 * (double)i / 48.0);  // 10000^{-i/48}
  double f = (double)s * inv;
  ct[idx] = (float)cos(f);
  st[idx] = (float)sin(f);
}

__global__ __launch_bounds__(256) void embed_k(const int* __restrict__ ids,
    const float* __restrict__ emb, float* __restrict__ x) {
  int bs = blockIdx.x;
  int id = ids[bs];
  const float4* src = (const float4*)(emb + (size_t)id*3072);
  float4* dst = (float4*)(x + (size_t)bs*3072);
  #pragma unroll
  for (int c = 0; c < 3; ++c) dst[threadIdx.x + 256*c] = src[threadIdx.x + 256*c];
}

template<int BF16OUT>
__global__ __launch_bounds__(256) void rmsnorm_k(const float* __restrict__ x, size_t rstride,
    const float* __restrict__ w, void* __restrict__ outv, size_t ostride) {
  int row = blockIdx.x, t = threadIdx.x;
  const float4* xr = (const float4*)(x + (size_t)row*rstride);
  float4 xv[3];
  float ss = 0.f;
  #pragma unroll
  for (int c = 0; c < 3; ++c) {
    xv[c] = xr[t + 256*c];
    ss += xv[c].x*xv[c].x + xv[c].y*xv[c].y + xv[c].z*xv[c].z + xv[c].w*xv[c].w;
  }
  ss = blk_sum(ss);
  float rs = 1.0f / sqrtf(ss * (1.0f/3072.0f) + 1e-5f);
  const float4* wr = (const float4*)w;
  #pragma unroll
  for (int c = 0; c < 3; ++c) {
    float4 wv = wr[t + 256*c];
    float o0 = xv[c].x*rs*wv.x, o1 = xv[c].y*rs*wv.y, o2 = xv[c].z*rs*wv.z, o3 = xv[c].w*rs*wv.w;
    if (BF16OUT) {
      ushort4 s4 = make_ushort4(f2bf(o0), f2bf(o1), f2bf(o2), f2bf(o3));
      ((ushort4*)((unsigned short*)outv + (size_t)row*ostride))[t + 256*c] = s4;
    } else {
      ((float4*)((float*)outv + (size_t)row*ostride))[t + 256*c] = make_float4(o0, o1, o2, o3);
    }
  }
}

// qkv fp32 [1024,9216] -> q,k bf16 [B,NH,S,96] with RoPE (q pre-scaled 1/sqrt(96))
__global__ __launch_bounds__(256) void rope_split_k(const float* __restrict__ qkv,
    const float* __restrict__ ct, const float* __restrict__ st,
    unsigned short* __restrict__ qo, unsigned short* __restrict__ ko) {
  int bs = blockIdx.x, b = bs >> 9, s = bs & 511;
  const float* base = qkv + (size_t)bs*9216;
  const float scale = 0.10206207261596577f;   // 1/sqrt(96)
  #pragma unroll
  for (int it = 0; it < 6; ++it) {
    int idx = it*256 + threadIdx.x;            // < 1536
    int hd = idx / 48, d = idx - hd*48;
    float c = ct[s*48 + d], sn = st[s*48 + d];
    size_t o = ((size_t)(b*32 + hd)*512 + s)*96 + d;
    float a0 = base[hd*96 + d], a1 = base[hd*96 + d + 48];
    qo[o]      = f2bf((a0*c - a1*sn)*scale);
    qo[o + 48] = f2bf((a1*c + a0*sn)*scale);
    float k0v = base[3072 + hd*96 + d], k1v = base[3072 + hd*96 + d + 48];
    ko[o]      = f2bf(k0v*c - k1v*sn);
    ko[o + 48] = f2bf(k1v*c + k0v*sn);
  }
}

// v (cols 6144..9215 of qkv) -> vT bf16 [z][d(128 pad)][s]
__global__ __launch_bounds__(256) void vtrans_k(const float* __restrict__ qkv,
    unsigned short* __restrict__ vT) {
  int z = blockIdx.x, b = z >> 5, hd = z & 31;
  __shared__ float tile[96][65];
  int t = threadIdx.x;
  for (int s0 = 0; s0 < 512; s0 += 64) {
    #pragma unroll
    for (int it = 0; it < 6; ++it) {
      int flat = it*256 + t;                   // < 1536
      int sl = flat / 24, c4 = flat - 24*sl;
      float4 vv = *(const float4*)(qkv + (size_t)(b*512 + s0 + sl)*9216 + 6144 + hd*96 + c4*4);
      tile[c4*4+0][sl] = vv.x; tile[c4*4+1][sl] = vv.y;
      tile[c4*4+2][sl] = vv.z; tile[c4*4+3][sl] = vv.w;
    }
    __syncthreads();
    #pragma unroll
    for (int it = 0; it < 6; ++it) {
      int flat = it*256 + t;                   // < 1536
      int d = flat >> 4, c = flat & 15;
      ushort4 o = make_ushort4(f2bf(tile[d][c*4]),   f2bf(tile[d][c*4+1]),
                               f2bf(tile[d][c*4+2]), f2bf(tile[d][c*4+3]));
      *(ushort4*)(vT + (size_t)z*65536 + (size_t)d*512 + s0 + c*4) = o;
    }
    __syncthreads();
  }
}

// causal+mask softmax over scores rows, fp32 in -> bf16 out. One wave per row.
__global__ __launch_bounds__(256) void softmax_k(const float* __restrict__ sc,
    const int* __restrict__ am, unsigned short* __restrict__ P) {
  int row = blockIdx.x*4 + (threadIdx.x >> 6);
  int l = threadIdx.x & 63;
  int qpos = row & 511, z = row >> 9, b = z >> 5;
  const float4* sr = (const float4*)(sc + (size_t)row*512);
  float4 v0 = sr[l*2], v1 = sr[l*2+1];
  float vals[8] = {v0.x, v0.y, v0.z, v0.w, v1.x, v1.y, v1.z, v1.w};
  const int* mk = am + b*512;
  float m = -3.4e38f;
  bool ok[8];
  #pragma unroll
  for (int j = 0; j < 8; ++j) {
    int c = l*8 + j;
    ok[j] = (c <= qpos) && (mk[c] != 0);
    if (ok[j]) m = fmaxf(m, vals[j]);
  }
  #pragma unroll
  for (int off = 32; off; off >>= 1) m = fmaxf(m, __shfl_xor(m, off, 64));
  float sum = 0.f, e[8];
  #pragma unroll
  for (int j = 0; j < 8; ++j) { e[j] = ok[j] ? __expf(vals[j] - m) : 0.f; sum += e[j]; }
  #pragma unroll
  for (int off = 32; off; off >>= 1) sum += __shfl_xor(sum, off, 64);
  float inv = 1.f / sum;
  uint4 o;
  o.x = (unsigned int)f2bf(e[0]*inv) | ((unsigned int)f2bf(e[1]*inv) << 16);
  o.y = (unsigned int)f2bf(e[2]*inv) | ((unsigned int)f2bf(e[3]*inv) << 16);
  o.z = (unsigned int)f2bf(e[4]*inv) | ((unsigned int)f2bf(e[5]*inv) << 16);
  o.w = (unsigned int)f2bf(e[6]*inv) | ((unsigned int)f2bf(e[7]*inv) << 16);
  ((uint4*)(P + (size_t)row*512))[l] = o;
}

// gu fp32 [1024,16384] -> ff bf16 [1024,8192]: up * silu(gate)
__global__ __launch_bounds__(256) void swiglu_k(const float* __restrict__ gu,
    unsigned short* __restrict__ ff) {
  int idx = blockIdx.x*256 + threadIdx.x;      // over 1024*2048 float4s
  int m = idx >> 11, j4 = idx & 2047;
  const float* rowp = gu + (size_t)m*16384;
  float4 gg = ((const float4*)rowp)[j4];
  float4 uu = ((const float4*)(rowp + 8192))[j4];
  float r0 = uu.x * gg.x / (1.f + __expf(-gg.x));
  float r1 = uu.y * gg.y / (1.f + __expf(-gg.y));
  float r2 = uu.z * gg.z / (1.f + __expf(-gg.z));
  float r3 = uu.w * gg.w / (1.f + __expf(-gg.w));
  ((ushort4*)(ff + (size_t)m*8192))[j4] = make_ushort4(f2bf(r0), f2bf(r1), f2bf(r2), f2bf(r3));
}

// h[b][j] = relu(xn[b] . w1[j] + b1[j]), j per wave (grid 48 x B, 4 j per wave)
__global__ __launch_bounds__(256) void head1_k(const float* __restrict__ xn,
    const float* __restrict__ w1, const float* __restrict__ b1, float* __restrict__ hc) {
  int b = blockIdx.y; int w = threadIdx.x >> 6, l = threadIdx.x & 63;
  const float4* xr = (const float4*)(xn + (size_t)b*3072);
  float4 xv[12];
  #pragma unroll
  for (int c = 0; c < 12; ++c) xv[c] = xr[l + 64*c];
  #pragma unroll
  for (int jj = 0; jj < 4; ++jj) {
    int j = blockIdx.x*16 + w*4 + jj;
    const float4* wr = (const float4*)(w1 + (size_t)j*3072);
    float p = 0.f;
    #pragma unroll
    for (int c = 0; c < 12; ++c) {
      float4 wv = wr[l + 64*c];
      p += xv[c].x*wv.x + xv[c].y*wv.y + xv[c].z*wv.z + xv[c].w*wv.w;
    }
    #pragma unroll
    for (int off = 32; off; off >>= 1) p += __shfl_xor(p, off, 64);
    if (l == 0) hc[b*768 + j] = fmaxf(p + b1[j], 0.f);
  }
}

// LayerNorm(768) + 2-way linear -> out logits
__global__ __launch_bounds__(256) void head2_k(const float* __restrict__ hc,
    const float* __restrict__ g, const float* __restrict__ be,
    const float* __restrict__ w2, const float* __restrict__ b2, float* __restrict__ out) {
  int b = blockIdx.x, t = threadIdx.x;
  float v[3];
  #pragma unroll
  for (int c = 0; c < 3; ++c) v[c] = hc[b*768 + t + 256*c];
  float s1 = v[0] + v[1] + v[2];
  float s2 = v[0]*v[0] + v[1]*v[1] + v[2]*v[2];
  s1 = blk_sum(s1); s2 = blk_sum(s2);
  float mu = s1 * (1.f/768.f);
  float var = s2 * (1.f/768.f) - mu*mu;
  float rs = 1.f / sqrtf(var + 1e-5f);
  float p0 = 0.f, p1 = 0.f;
  #pragma unroll
  for (int c = 0; c < 3; ++c) {
    int j = t + 256*c;
    float hn = (v[c] - mu)*rs*g[j] + be[j];
    p0 += hn * w2[j]; p1 += hn * w2[768 + j];
  }
  p0 = blk_sum(p0); p1 = blk_sum(p1);
  if (t == 0) { out[b*2] = p0 + b2[0]; out[b*2 + 1] = p1 + b2[1]; }
}

// ===========================================================================
extern "C" void kernel_launch(void* const* d_in, const int* in_sizes, int n_in,
                              void* d_out, int out_size, void* d_ws, size_t ws_size,
                              hipStream_t stream) {
  const int*   ids   = (const int*)d_in[0];
  const int*   amask = (const int*)d_in[1];
  const float* emb   = (const float*)d_in[2];
  const int*   qkvP  = (const int*)d_in[3];
  const float* qkvA  = (const float*)d_in[4];
  const int*   oP    = (const int*)d_in[5];
  const float* oA    = (const float*)d_in[6];
  const int*   guP   = (const int*)d_in[7];
  const float* guA   = (const float*)d_in[8];
  const int*   dnP   = (const int*)d_in[9];
  const float* dnA   = (const float*)d_in[10];
  const float* ln1   = (const float*)d_in[11];
  const float* ln2   = (const float*)d_in[12];
  const float* flw   = (const float*)d_in[13];
  const float* w1    = (const float*)d_in[14];
  const float* b1    = (const float*)d_in[15];
  const float* lng   = (const float*)d_in[16];
  const float* lnb   = (const float*)d_in[17];
  const float* w2    = (const float*)d_in[18];
  const float* b2    = (const float*)d_in[19];
  float* out = (float*)d_out;

  char* ws = (char*)d_ws;
  float*          x    = (float*)(ws + 0);
  unsigned short* h    = (unsigned short*)(ws + 12582912);
  float*          big  = (float*)(ws + 18874368);
  unsigned short* P    = (unsigned short*)(ws + 85983232);
  unsigned short* q    = (unsigned short*)(ws + 119537664);
  unsigned short* k    = (unsigned short*)(ws + 125829120);
  unsigned short* vT   = (unsigned short*)(ws + 132120576);
  unsigned short* ctx  = (unsigned short*)(ws + 140509184);
  unsigned short* ff   = (unsigned short*)(ws + 146800640);
  float*          ctab = (float*)(ws + 163577856);
  float*          stab = (float*)(ws + 163676160);
  float*          xn   = (float*)(ws + 163774464);
  float*          hcls = (float*)(ws + 163799040);

  rope_table_k<<<96, 256, 0, stream>>>(ctab, stab);
  embed_k<<<1024, 256, 0, stream>>>(ids, emb, x);

  for (int l = 0; l < 2; ++l) {
    // --- attention ---
    rmsnorm_k<1><<<1024, 256, 0, stream>>>(x, 3072, ln1 + l*3072, h, 3072);
    gemm_k<1,0><<<dim3(72,8,1), 256, 0, stream>>>(
        h, 3072, 0, 0, nullptr, 0, 0, 0,
        qkvP + (size_t)l*3538944, qkvA + (size_t)l*442368,
        big, 9216, 0, 0, 1024, 9216, 3072);
    rope_split_k<<<1024, 256, 0, stream>>>(big, ctab, stab, q, k);
    vtrans_k<<<64, 256, 0, stream>>>(big, vT);
    gemm_k<0,0><<<dim3(4,4,64), 256, 0, stream>>>(
        q, 96, 1572864, 49152, k, 96, 1572864, 49152, nullptr, nullptr,
        big, 512, 8388608, 262144, 512, 512, 96);
    softmax_k<<<8192, 256, 0, stream>>>(big, amask, P);
    gemm_k<0,2><<<dim3(1,4,64), 256, 0, stream>>>(
        P, 512, 8388608, 262144, vT, 512, 2097152, 65536, nullptr, nullptr,
        ctx, 3072, 1572864, 96, 512, 96, 512);
    gemm_k<1,1><<<dim3(24,8,1), 256, 0, stream>>>(
        ctx, 3072, 0, 0, nullptr, 0, 0, 0,
        oP + (size_t)l*1179648, oA + (size_t)l*147456,
        x, 3072, 0, 0, 1024, 3072, 3072);
    // --- gated MLP ---
    rmsnorm_k<1><<<1024, 256, 0, stream>>>(x, 3072, ln2 + l*3072, h, 3072);
    gemm_k<1,0><<<dim3(128,8,1), 256, 0, stream>>>(
        h, 3072, 0, 0, nullptr, 0, 0, 0,
        guP + (size_t)l*6291456, guA + (size_t)l*786432,
        big, 16384, 0, 0, 1024, 16384, 3072);
    swiglu_k<<<8192, 256, 0, stream>>>(big, ff);
    gemm_k<1,1><<<dim3(24,8,1), 256, 0, stream>>>(
        ff, 8192, 0, 0, nullptr, 0, 0, 0,
        dnP + (size_t)l*3145728, dnA + (size_t)l*393216,
        x, 3072, 0, 0, 1024, 3072, 8192);
  }

  // --- final norm (last token only) + cls head ---
  rmsnorm_k<0><<<2, 256, 0, stream>>>(x + (size_t)511*3072, 1572864, flw, xn, 3072);
  head1_k<<<dim3(48,2,1), 256, 0, stream>>>(xn, w1, b1, hcls);
  head2_k<<<2, 256, 0, stream>>>(hcls, lng, lnb, w2, b2, out);
}